// Round 2
// baseline (88.886 us; speedup 1.0000x reference)
//
#include <hip/hip_runtime.h>
#include <math.h>

// Problem constants (match reference)
#define NTOT   5040000          // NT
#define NFORC  84000            // NF
#define NSTEPS (NTOT - 1)       // 5,039,999 model steps (it = 0..NT-2)

#define TPB    256
#define SEGS   60               // steps per thread == NSUB: segment = one forcing interval
#define WIN    (TPB * SEGS)     // 15360
#define WARM   4800             // redundant warm-up steps; |a|^4800 ~ 2e-6 => error ~1e-7
#define CHUNK  (WIN - WARM)     // 10560 owned output steps per block
#define NBLK   ((NSTEPS + CHUNK - 1) / CHUNK)   // 478 -> all co-resident (<= 512)

// ---- complex double helpers (uniform per-thread constant derivation) ----
struct cd { double x, y; };
__device__ __forceinline__ cd cmuld(cd a, cd b){ return {a.x*b.x - a.y*b.y, a.x*b.y + a.y*b.x}; }
__device__ __forceinline__ cd cdivd(cd a, cd b){
    double r = 1.0 / (b.x*b.x + b.y*b.y);
    return {(a.x*b.x + a.y*b.y)*r, (a.y*b.x - a.x*b.y)*r};
}

// ---- complex float helpers ----
__device__ __forceinline__ float2 cfma(float2 m, float2 p, float2 v) {
    // v + m*p
    v.x = fmaf(m.x, p.x, fmaf(-m.y, p.y, v.x));
    v.y = fmaf(m.x, p.y, fmaf( m.y, p.x, v.y));
    return v;
}
__device__ __forceinline__ float2 cmulf(float2 a, float2 b){
    return make_float2(a.x*b.x - a.y*b.y, a.x*b.y + a.y*b.x);
}

__global__ __launch_bounds__(TPB, 4)
void slab_kernel(const float* __restrict__ pk,
                 const float* __restrict__ TAx,
                 const float* __restrict__ TAy,
                 float* __restrict__ out)
{
    __shared__ float2 wk[4];    // cross-wave carries only

    const int tid  = threadIdx.x;
    const int lane = tid & 63;
    const int wv   = tid >> 6;
    const int blk  = blockIdx.x;

    // ---- model parameters (f64 for the constant derivation; trivial op count) ----
    const double K0 = exp((double)pk[0]);
    const double K1 = exp((double)pk[1]);
    const cd a   = {1.0 - 60.0 * K1, -60.0e-4};        // a = 1 + dt*(-i*fc - K1), dt=60, fc=1e-4
    const double s = 60.0 * K0;                         // b_t = s * TAi_t

    // alpha = a^60 by square-and-multiply
    cd alpha = {1.0, 0.0};
    {
        cd p = a; int e = SEGS;
        while (e) { if (e & 1) alpha = cmuld(alpha, p); p = cmuld(p, p); e >>= 1; }
    }
    // G = sum_{j=0}^{59} a^j = (a^60 - 1)/(a - 1)
    const cd am1 = {a.x - 1.0, a.y};
    const cd G = cdivd({alpha.x - 1.0, alpha.y}, am1);
    // T = sum_{j=0}^{59} j a^j = a*(1 - 60 a^59 + 59 a^60)/(1-a)^2
    const cd a59 = cdivd(alpha, a);
    const cd one_m_a = {-am1.x, -am1.y};
    cd num = {1.0 - 60.0*a59.x + 59.0*alpha.x, -60.0*a59.y + 59.0*alpha.y};
    const cd T = cdivd(cmuld(a, num), cmuld(one_m_a, one_m_a));
    // H = sum_{j} (59-j) a^j = 59G - T
    const cd H = {59.0*G.x - T.x, 59.0*G.y - T.y};

    const float2 Gf = make_float2((float)G.x, (float)G.y);
    const float2 Hf = make_float2((float)H.x, (float)H.y);
    // apf[k] = alpha^(2^k), k=0..5; beta = alpha^64
    float2 apf[6];
    float2 betaf;
    {
        cd p = alpha;
        #pragma unroll
        for (int k = 0; k < 6; ++k) { apf[k] = make_float2((float)p.x, (float)p.y); p = cmuld(p, p); }
        betaf = make_float2((float)p.x, (float)p.y);
    }
    const float ar  = (float)a.x;
    const float aii = (float)a.y;

    // ---- window / ownership ----
    const int wstart = blk * CHUNK;
    const int wend   = min(wstart + CHUNK, NSTEPS);
    const int ws     = max(0, wstart - WARM);   // multiple of 60
    const int seg    = ws + tid * SEGS;         // first model step of this thread

    // ---- forcing (coalesced: 2 consecutive samples per thread) ----
    const int itf = ws / SEGS + tid;
    const int i0  = min(itf,     NFORC - 1);
    const int i1  = min(itf + 1, NFORC - 1);
    const float x0 = TAx[i0], y0 = TAy[i0];
    const float x1 = TAx[i1], y1 = TAy[i1];
    const float sF = (float)s;
    const float2 b0 = make_float2(sF * x0, sF * y0);
    const float  ci = sF * (1.0f / 60.0f);
    const float2 db = make_float2((x1 - x0) * ci, (y1 - y0) * ci);

    // ---- closed-form local carry over 60 steps from u=0: c = G*b0 + H*db ----
    float2 S = cfma(Gf, b0, cmulf(Hf, db));

    // ---- wave-level inclusive affine scan (uniform coefficient alpha) ----
    #pragma unroll
    for (int k = 0; k < 6; ++k) {
        const int off = 1 << k;
        float px = __shfl_up(S.x, off, 64);
        float py = __shfl_up(S.y, off, 64);
        if (lane < off) { px = 0.f; py = 0.f; }
        S = cfma(apf[k], make_float2(px, py), S);
    }
    // exclusive-by-one within wave
    float ex = __shfl_up(S.x, 1, 64);
    float ey = __shfl_up(S.y, 1, 64);
    if (lane == 0) { ex = 0.f; ey = 0.f; }

    // cross-wave carries (one barrier total)
    if (lane == 63) wk[wv] = S;
    __syncthreads();
    float2 C = make_float2(0.f, 0.f);
    if (wv >= 1) C = wk[0];
    if (wv >= 2) C = cfma(betaf, C, wk[1]);     // K1 + beta*K0
    if (wv == 3) C = cfma(betaf, C, wk[2]);     // K2 + beta*(K1 + beta*K0)

    // alpha^lane via binary decomposition
    float2 al = make_float2(1.f, 0.f);
    #pragma unroll
    for (int k = 0; k < 6; ++k)
        if (lane & (1 << k)) al = cmulf(al, apf[k]);

    // u_start = exclusive-within-wave + alpha^lane * C_{w-1}
    float2 u0 = cfma(al, C, make_float2(ex, ey));

    if (blk == 0 && tid == 0) { out[0] = 0.f; out[NTOT] = 0.f; }   // U[0] = 0

    // ---- pass 2: generate the 60 owned outputs (contiguous per thread) ----
    const bool live = (seg >= wstart);
    const int  nv   = wend - seg;               // valid steps (may be <=0 or >=60)
    if (!live || nv <= 0) return;               // warm threads / beyond-end threads exit

    float ur = u0.x, ui = u0.y;
    float bre = b0.x, bim = b0.y;
    const float dbx = db.x, dby = db.y;
    float* __restrict__ pr = out + (seg + 1);
    float* __restrict__ pi = out + (NTOT + seg + 1);

#define STEP() do { \
        float nr_ = fmaf(ar, ur, fmaf(-aii, ui, bre)); \
        float ni_ = fmaf(ar, ui, fmaf( aii, ur, bim)); \
        ur = nr_; ui = ni_; bre += dbx; bim += dby; } while (0)

    if (nv >= SEGS) {
        // fast path: full segment; head 3 dwords, 14 x float4 (16B-aligned), tail 1 dword
        #pragma unroll
        for (int k = 0; k < 3; ++k) { STEP(); pr[k] = ur; pi[k] = ui; }
        #pragma unroll
        for (int g = 0; g < 14; ++g) {
            float4 vr, vi;
            STEP(); vr.x = ur; vi.x = ui;
            STEP(); vr.y = ur; vi.y = ui;
            STEP(); vr.z = ur; vi.z = ui;
            STEP(); vr.w = ur; vi.w = ui;
            *reinterpret_cast<float4*>(pr + 3 + 4*g) = vr;
            *reinterpret_cast<float4*>(pi + 3 + 4*g) = vi;
        }
        STEP(); pr[59] = ur; pi[59] = ui;
    } else {
        // slow path: at most one partial thread in the whole grid
        for (int k = 0; k < SEGS; ++k) {
            STEP();
            if (k < nv) { pr[k] = ur; pi[k] = ui; }
        }
    }
#undef STEP
}

extern "C" void kernel_launch(void* const* d_in, const int* in_sizes, int n_in,
                              void* d_out, int out_size, void* d_ws, size_t ws_size,
                              hipStream_t stream)
{
    const float* pk  = (const float*)d_in[0];
    const float* TAx = (const float*)d_in[1];
    const float* TAy = (const float*)d_in[2];
    float* out = (float*)d_out;

    slab_kernel<<<dim3(NBLK), dim3(TPB), 0, stream>>>(pk, TAx, TAy, out);
}

// Round 3
// 80.804 us; speedup vs baseline: 1.1000x; 1.1000x over previous
//
#include <hip/hip_runtime.h>
#include <math.h>

// Problem constants (match reference)
#define NTOT   5040000          // NT
#define NFORC  84000            // NF
#define NSTEPS (NTOT - 1)       // 5,039,999 model steps (it = 0..NT-2)

#define TPB    256
#define SEGS   60               // steps per segment == NSUB: segment = one forcing interval
#define WIN    (TPB * SEGS)     // 15360
#define WARM   4800             // redundant warm-up steps; |a|^4800 ~ 2e-6 => error ~1e-7
#define CHUNK  (WIN - WARM)     // 10560 owned output steps per block
#define NBLK   ((NSTEPS + CHUNK - 1) / CHUNK)   // 478

// ---- complex double helpers ----
struct cd { double x, y; };
__device__ __forceinline__ cd cmuld(cd a, cd b){ return {a.x*b.x - a.y*b.y, a.x*b.y + a.y*b.x}; }
__device__ __forceinline__ cd cdivd(cd a, cd b){
    double r = 1.0 / (b.x*b.x + b.y*b.y);
    return {(a.x*b.x + a.y*b.y)*r, (a.y*b.x - a.x*b.y)*r};
}
__device__ __forceinline__ cd cpowd(cd a, int e){
    cd r = {1.0, 0.0}; cd p = a;
    while (e) { if (e & 1) r = cmuld(r, p); p = cmuld(p, p); e >>= 1; }
    return r;
}

// ---- complex float helpers ----
__device__ __forceinline__ float2 cfma(float2 m, float2 p, float2 v) {   // v + m*p
    v.x = fmaf(m.x, p.x, fmaf(-m.y, p.y, v.x));
    v.y = fmaf(m.x, p.y, fmaf( m.y, p.x, v.y));
    return v;
}
__device__ __forceinline__ float2 cmulf(float2 a, float2 b){
    return make_float2(a.x*b.x - a.y*b.y, a.x*b.y + a.y*b.x);
}

__global__ __launch_bounds__(TPB, 4)
void slab_kernel(const float* __restrict__ pk,
                 const float* __restrict__ TAx,
                 const float* __restrict__ TAy,
                 float* __restrict__ out)
{
    // LDS: step tables (indexed by r = step-within-segment) + per-segment params
    __shared__ float2 sA[SEGS], sG[SEGS], sH[SEGS];      // a^{r+1}, G_{r+1}, H_{r+1}
    __shared__ float2 sU0[TPB], sB0[TPB], sDB[TPB];      // per-segment u_start, b0, db
    __shared__ float2 wk[4];                              // cross-wave scan carries

    const int tid  = threadIdx.x;
    const int lane = tid & 63;
    const int wv   = tid >> 6;
    const int blk  = blockIdx.x;

    // ---- model parameters (f64 derivation, uniform) ----
    const double K0 = exp((double)pk[0]);
    const double K1 = exp((double)pk[1]);
    const cd a   = {1.0 - 60.0 * K1, -60.0e-4};          // a = 1 + dt*(-i*fc - K1)
    const double s = 60.0 * K0;                           // b_t = s * TAi_t
    const cd am1     = {a.x - 1.0, a.y};
    const cd one_m_a = {-am1.x, -am1.y};
    const cd om2     = cmuld(one_m_a, one_m_a);

    // alpha = a^60 and derived segment-level constants
    const cd alpha = cpowd(a, SEGS);
    const cd G60 = cdivd({alpha.x - 1.0, alpha.y}, am1);
    const cd a59 = cdivd(alpha, a);
    cd num60 = {1.0 - 60.0*a59.x + 59.0*alpha.x, -60.0*a59.y + 59.0*alpha.y};
    const cd T60 = cdivd(cmuld(a, num60), om2);
    const cd H60 = {59.0*G60.x - T60.x, 59.0*G60.y - T60.y};

    const float2 Gf = make_float2((float)G60.x, (float)G60.y);
    const float2 Hf = make_float2((float)H60.x, (float)H60.y);
    float2 apf[6]; float2 betaf;
    {
        cd p = alpha;
        #pragma unroll
        for (int k = 0; k < 6; ++k) { apf[k] = make_float2((float)p.x, (float)p.y); p = cmuld(p, p); }
        betaf = make_float2((float)p.x, (float)p.y);     // alpha^64
    }

    // ---- per-step tables: thread r (< 60) computes j = r+1 ----
    if (tid < SEGS) {
        const int j = tid + 1;
        const cd aj = cpowd(a, j);
        const cd Gj = cdivd({aj.x - 1.0, aj.y}, am1);
        const cd ajm1 = cdivd(aj, a);
        cd nm = {1.0 - (double)j*ajm1.x + (double)(j-1)*aj.x,
                      - (double)j*ajm1.y + (double)(j-1)*aj.y};
        const cd Tj = cdivd(cmuld(a, nm), om2);
        const cd Hj = {(double)(j-1)*Gj.x - Tj.x, (double)(j-1)*Gj.y - Tj.y};
        sA[tid] = make_float2((float)aj.x, (float)aj.y);
        sG[tid] = make_float2((float)Gj.x, (float)Gj.y);
        sH[tid] = make_float2((float)Hj.x, (float)Hj.y);
    }

    // ---- window / segment geometry ----
    const int wstart = blk * CHUNK;
    const int wend   = min(wstart + CHUNK, NSTEPS);
    const int ws     = max(0, wstart - WARM);            // multiple of 60

    // ---- forcing for this thread's segment (coalesced) ----
    const int itf = ws / SEGS + tid;
    const int i0  = min(itf,     NFORC - 1);
    const int i1  = min(itf + 1, NFORC - 1);
    const float x0 = TAx[i0], y0 = TAy[i0];
    const float x1 = TAx[i1], y1 = TAy[i1];
    const float sF = (float)s;
    const float2 b0 = make_float2(sF * x0, sF * y0);
    const float  ci = sF * (1.0f / 60.0f);
    const float2 db = make_float2((x1 - x0) * ci, (y1 - y0) * ci);
    sB0[tid] = b0;
    sDB[tid] = db;

    // ---- closed-form segment carry from u=0: S = G60*b0 + H60*db ----
    float2 S = cfma(Gf, b0, cmulf(Hf, db));

    // ---- wave-level inclusive affine scan (uniform coefficient alpha) ----
    #pragma unroll
    for (int k = 0; k < 6; ++k) {
        const int off = 1 << k;
        float px = __shfl_up(S.x, off, 64);
        float py = __shfl_up(S.y, off, 64);
        if (lane < off) { px = 0.f; py = 0.f; }
        S = cfma(apf[k], make_float2(px, py), S);
    }
    float ex = __shfl_up(S.x, 1, 64);
    float ey = __shfl_up(S.y, 1, 64);
    if (lane == 0) { ex = 0.f; ey = 0.f; }

    if (lane == 63) wk[wv] = S;
    __syncthreads();                                      // wk + tables visible
    float2 C = make_float2(0.f, 0.f);
    if (wv >= 1) C = wk[0];
    if (wv >= 2) C = cfma(betaf, C, wk[1]);
    if (wv == 3) C = cfma(betaf, C, wk[2]);

    float2 al = make_float2(1.f, 0.f);                    // alpha^lane
    #pragma unroll
    for (int k = 0; k < 6; ++k)
        if (lane & (1 << k)) al = cmulf(al, apf[k]);

    const float2 u0 = cfma(al, C, make_float2(ex, ey));   // segment start state
    sU0[tid] = u0;
    __syncthreads();                                      // params visible

    if (blk == 0 && tid == 0) { out[0] = 0.f; out[NTOT] = 0.f; }   // U[0] = 0

    // ---- drain: output-index order, coalesced float4 stores ----
    // output element q (plane offset 0 / NTOT) with q = o+1, o in [wstart, wend):
    //   m = o - ws; seg = m/60; r = m%60; U = a^{r+1}*u0 + G_{r+1}*b0 + H_{r+1}*db
    const int qlo = wstart + 1;
    const int qhi = wend + 1;
    const int g0  = qlo & ~3;
    const int ng  = (qhi - g0 + 3) >> 2;                  // number of 4-float groups

    for (int k = tid; k < ng; k += TPB) {
        const int q4 = g0 + (k << 2);
        float re[4], im[4];
        #pragma unroll
        for (int e = 0; e < 4; ++e) {
            const int q = q4 + e;
            if (q < qlo || q >= qhi) { re[e] = 0.f; im[e] = 0.f; continue; }
            const int m   = q - 1 - ws;
            const int seg = (int)((unsigned)m / 60u);
            const int r   = m - seg * 60;
            const float2 A  = sA[r];
            const float2 Gv = sG[r];
            const float2 Hv = sH[r];
            float2 u = cmulf(A, sU0[seg]);
            u = cfma(Gv, sB0[seg], u);
            u = cfma(Hv, sDB[seg], u);
            re[e] = u.x; im[e] = u.y;
        }
        if (q4 >= qlo && q4 + 4 <= qhi) {
            *reinterpret_cast<float4*>(out + q4)        = make_float4(re[0], re[1], re[2], re[3]);
            *reinterpret_cast<float4*>(out + NTOT + q4) = make_float4(im[0], im[1], im[2], im[3]);
        } else {
            #pragma unroll
            for (int e = 0; e < 4; ++e) {
                const int q = q4 + e;
                if (q >= qlo && q < qhi) { out[q] = re[e]; out[NTOT + q] = im[e]; }
            }
        }
    }
}

extern "C" void kernel_launch(void* const* d_in, const int* in_sizes, int n_in,
                              void* d_out, int out_size, void* d_ws, size_t ws_size,
                              hipStream_t stream)
{
    const float* pk  = (const float*)d_in[0];
    const float* TAx = (const float*)d_in[1];
    const float* TAy = (const float*)d_in[2];
    float* out = (float*)d_out;

    slab_kernel<<<dim3(NBLK), dim3(TPB), 0, stream>>>(pk, TAx, TAy, out);
}

// Round 4
// 78.546 us; speedup vs baseline: 1.1316x; 1.0287x over previous
//
#include <hip/hip_runtime.h>
#include <math.h>

// Problem constants (match reference)
#define NTOT   5040000          // NT
#define NFORC  84000            // NF
#define NSTEPS (NTOT - 1)       // 5,039,999 model steps (it = 0..NT-2)

#define TPB    256
#define SEGS   60               // steps per segment == NSUB (one forcing interval)
#define WIN    (TPB * SEGS)     // 15360 steps per block window
#define WARM   4800             // redundant warm-up; |a|^4800 ~ 2e-6 => error ~1e-7
#define CHUNK  (WIN - WARM)     // 10560 owned output steps per block
#define NBLK   ((NSTEPS + CHUNK - 1) / CHUNK)   // 478
#define RSEG   64               // segments staged per round (= one wave)
#define RSPAN  (RSEG * SEGS)    // 3840 steps per round
#define LSTR   61               // LDS row stride in floats (odd => conflict-free)

// ---- complex double helpers (uniform constant derivation) ----
struct cd { double x, y; };
__device__ __forceinline__ cd cmuld(cd a, cd b){ return {a.x*b.x - a.y*b.y, a.x*b.y + a.y*b.x}; }
__device__ __forceinline__ cd cdivd(cd a, cd b){
    double r = 1.0 / (b.x*b.x + b.y*b.y);
    return {(a.x*b.x + a.y*b.y)*r, (a.y*b.x - a.x*b.y)*r};
}
__device__ __forceinline__ cd cpowd(cd a, int e){
    cd r = {1.0, 0.0}; cd p = a;
    while (e) { if (e & 1) r = cmuld(r, p); p = cmuld(p, p); e >>= 1; }
    return r;
}

// ---- complex float helpers ----
__device__ __forceinline__ float2 cfma(float2 m, float2 p, float2 v) {   // v + m*p
    v.x = fmaf(m.x, p.x, fmaf(-m.y, p.y, v.x));
    v.y = fmaf(m.x, p.y, fmaf( m.y, p.x, v.y));
    return v;
}
__device__ __forceinline__ float2 cmulf(float2 a, float2 b){
    return make_float2(a.x*b.x - a.y*b.y, a.x*b.y + a.y*b.x);
}

__global__ __launch_bounds__(TPB, 4)
void slab_kernel(const float* __restrict__ pk,
                 const float* __restrict__ TAx,
                 const float* __restrict__ TAy,
                 float* __restrict__ out)
{
    __shared__ float  sRe[RSEG * LSTR];   // 15,616 B
    __shared__ float  sIm[RSEG * LSTR];   // 15,616 B
    __shared__ float2 wk[4];              // cross-wave scan carries

    const int tid  = threadIdx.x;
    const int lane = tid & 63;
    const int wv   = tid >> 6;
    const int blk  = blockIdx.x;

    // ---- model parameters (f64 derivation, uniform; short) ----
    const double K0 = exp((double)pk[0]);
    const double K1 = exp((double)pk[1]);
    const cd a   = {1.0 - 60.0 * K1, -60.0e-4};          // a = 1 + dt*(-i*fc - K1)
    const double s = 60.0 * K0;                           // b_t = s * TAi_t
    const cd am1     = {a.x - 1.0, a.y};
    const cd one_m_a = {-am1.x, -am1.y};
    const cd om2     = cmuld(one_m_a, one_m_a);

    const cd alpha = cpowd(a, SEGS);                      // a^60
    const cd G60 = cdivd({alpha.x - 1.0, alpha.y}, am1);  // sum a^j, j<60
    const cd a59 = cdivd(alpha, a);
    cd num60 = {1.0 - 60.0*a59.x + 59.0*alpha.x, -60.0*a59.y + 59.0*alpha.y};
    const cd T60 = cdivd(cmuld(a, num60), om2);           // sum j a^j
    const cd H60 = {59.0*G60.x - T60.x, 59.0*G60.y - T60.y};

    const float2 Gf = make_float2((float)G60.x, (float)G60.y);
    const float2 Hf = make_float2((float)H60.x, (float)H60.y);
    float2 apf[6]; float2 betaf;
    {
        cd p = alpha;
        #pragma unroll
        for (int k = 0; k < 6; ++k) { apf[k] = make_float2((float)p.x, (float)p.y); p = cmuld(p, p); }
        betaf = make_float2((float)p.x, (float)p.y);      // alpha^64
    }
    const float arf = (float)a.x;
    const float aif = (float)a.y;

    // ---- window / segment geometry ----
    const int wstart = blk * CHUNK;
    const int wend   = min(wstart + CHUNK, NSTEPS);
    const int ws     = max(0, wstart - WARM);             // multiple of 60

    // ---- forcing for this thread's segment (coalesced) ----
    const int itf = ws / SEGS + tid;
    const int i0  = min(itf,     NFORC - 1);
    const int i1  = min(itf + 1, NFORC - 1);
    const float x0 = TAx[i0], y0 = TAy[i0];
    const float x1 = TAx[i1], y1 = TAy[i1];
    const float sF = (float)s;
    const float2 b0 = make_float2(sF * x0, sF * y0);
    const float  ci = sF * (1.0f / 60.0f);
    const float2 db = make_float2((x1 - x0) * ci, (y1 - y0) * ci);

    // ---- closed-form segment carry from u=0: S = G60*b0 + H60*db ----
    float2 S = cfma(Gf, b0, cmulf(Hf, db));

    // ---- wave-level inclusive affine scan (uniform coefficient alpha) ----
    #pragma unroll
    for (int k = 0; k < 6; ++k) {
        const int off = 1 << k;
        float px = __shfl_up(S.x, off, 64);
        float py = __shfl_up(S.y, off, 64);
        if (lane < off) { px = 0.f; py = 0.f; }
        S = cfma(apf[k], make_float2(px, py), S);
    }
    float ex = __shfl_up(S.x, 1, 64);
    float ey = __shfl_up(S.y, 1, 64);
    if (lane == 0) { ex = 0.f; ey = 0.f; }

    if (lane == 63) wk[wv] = S;
    __syncthreads();
    float2 C = make_float2(0.f, 0.f);
    if (wv >= 1) C = wk[0];
    if (wv >= 2) C = cfma(betaf, C, wk[1]);
    if (wv == 3) C = cfma(betaf, C, wk[2]);

    float2 al = make_float2(1.f, 0.f);                    // alpha^lane
    #pragma unroll
    for (int k = 0; k < 6; ++k)
        if (lane & (1 << k)) al = cmulf(al, apf[k]);

    const float2 u0 = cfma(al, C, make_float2(ex, ey));   // this segment's start state

    if (blk == 0 && tid == 0) { out[0] = 0.f; out[NTOT] = 0.f; }   // U[0] = 0

    // ---- rounds: wave p stages its 64 segments; all threads drain linearly ----
    const int olo = wstart - ws;                          // first owned step (rel)
    const int ohi = wend - ws;                            // one past last owned (rel)

    for (int p = 0; p < 4; ++p) {
        const int lo = max(RSPAN * p, olo);               // uniform per block
        const int hi = min(RSPAN * p + RSPAN, ohi);
        if (hi <= lo) continue;                           // warm/empty round: skip

        if (wv == p) {
            // stage: 60-step recurrence for segment == tid, conflict-free writes
            float ur = u0.x, ui = u0.y;
            float bre = b0.x, bim = b0.y;
            const int base = lane * LSTR;
            #pragma unroll
            for (int r = 0; r < SEGS; ++r) {
                float nr = fmaf(arf, ur, fmaf(-aif, ui, bre));
                float ni = fmaf(arf, ui, fmaf( aif, ur, bim));
                ur = nr; ui = ni;
                bre += db.x; bim += db.y;
                sRe[base + r] = nr;
                sIm[base + r] = ni;
            }
        }
        __syncthreads();

        // drain: global steps m in [lo,hi), fully linear => perfect coalescing
        {
            int rel = lo + tid - RSPAN * p;               // 0..RSPAN-1
            int sseg = (int)((unsigned)rel / 60u);
            int k    = rel - sseg * 60;
            float* __restrict__ pr = out + (ws + 1);
            float* __restrict__ pi = out + (NTOT + ws + 1);
            for (int idx = lo + tid; idx < hi; idx += TPB) {
                const int addr = LSTR * sseg + k;
                pr[idx] = sRe[addr];
                pi[idx] = sIm[addr];
                // idx += 256 => rel += 256 = 4*60 + 16
                sseg += 4; k += 16;
                if (k >= SEGS) { k -= SEGS; sseg += 1; }
            }
        }
        __syncthreads();
    }
}

extern "C" void kernel_launch(void* const* d_in, const int* in_sizes, int n_in,
                              void* d_out, int out_size, void* d_ws, size_t ws_size,
                              hipStream_t stream)
{
    const float* pk  = (const float*)d_in[0];
    const float* TAx = (const float*)d_in[1];
    const float* TAy = (const float*)d_in[2];
    float* out = (float*)d_out;

    slab_kernel<<<dim3(NBLK), dim3(TPB), 0, stream>>>(pk, TAx, TAy, out);
}